// Round 7
// baseline (204.092 us; speedup 1.0000x reference)
//
#include <hip/hip_runtime.h>
#include <math.h>
#include <float.h>

#define D_DIM 768
#define K_C   256
#define NCH   24
#define MAXFIX 32768
#define MARGIN 1.5e-2f

typedef __attribute__((ext_vector_type(8))) short s16x8;
typedef __attribute__((ext_vector_type(4))) float f32x4;

__device__ inline unsigned short f2bf(float x) {      // RNE f32 -> bf16 bits
    unsigned u = __float_as_uint(x);
    unsigned r = 0x7FFFu + ((u >> 16) & 1u);
    return (unsigned short)((u + r) >> 16);
}
// pack trunc-bf16 of (a,b) -> u32 {lo16=hi(a), hi16=hi(b)} via v_perm
__device__ inline unsigned pk2(float a, float b) {
    return __builtin_amdgcn_perm(__float_as_uint(b), __float_as_uint(a), 0x07060302u);
}

// ---------------- prep: c2 (f64) + C -> chunk-major bf16 image [ch][256][32] ----------------
__global__ __launch_bounds__(256) void kprep(const float* __restrict__ C,
    short* __restrict__ Cimg, float* __restrict__ c2f, int* __restrict__ fix_cnt)
{
    const int k = blockIdx.x;       // centroid
    const int t = threadIdx.x;
    __shared__ double red[4];
    double s = 0.0;
#pragma unroll
    for (int i = 0; i < 3; ++i) {
        int d = t + 256*i;
        float x = C[(size_t)k*D_DIM + d];
        s += (double)x * (double)x;
        Cimg[(size_t)(d >> 5)*8192 + k*32 + (d & 31)] = (short)f2bf(x);
    }
#pragma unroll
    for (int m = 1; m < 64; m <<= 1) s += __shfl_xor(s, m, 64);
    if ((t & 63) == 0) red[t >> 6] = s;
    __syncthreads();
    if (t == 0) {
        c2f[k] = (float)(red[0] + red[1] + red[2] + red[3]);
        if (k == 0) *fix_cnt = 0;
    }
}

// ---------------- streaming MFMA kernel: each wave owns 16 rows x 256 cols ----------------
// No LDS staging, no barriers in the K loop. B-frags read from L2-resident Cimg,
// A-frags from the E stream (read exactly once).
__global__ __launch_bounds__(256, 4) void kdist(const float* __restrict__ E,
    const short* __restrict__ Cimg, const float* __restrict__ c2f,
    float* __restrict__ labels, float* __restrict__ partials,
    int* __restrict__ fix_cnt, int* __restrict__ fix_list)
{
    __shared__ float spart[4][K_C][3];       // softmin merge only (12 KB)

    const int t    = threadIdx.x;
    const int lane = t & 63;
    const int w    = t >> 6;
    const int c4   = lane & 15, sgr = lane >> 4;
    const int wid  = blockIdx.x*4 + w;       // 0..4095
    const int R0   = wid << 4;               // wave's 16 rows

    f32x4 acc[16];
#pragma unroll
    for (int n = 0; n < 16; ++n) acc[n] = (f32x4){0.f,0.f,0.f,0.f};

    // A: lane reads row (R0+c4), k-octet sgr  -> 32 B per chunk
    const float* Ep = E + (size_t)(R0 + c4)*D_DIM + sgr*8;
    // B: lane reads centroid (n*16+c4), k-octet sgr from image
    const short* Cb = Cimg + c4*32 + sgr*8;

    float e2p = 0.f;
    float4 q0 = *reinterpret_cast<const float4*>(Ep);
    float4 q1 = *reinterpret_cast<const float4*>(Ep + 4);

#pragma unroll 1
    for (int ch = 0; ch < NCH; ++ch) {
        // convert current E chunk, accumulate e2
        e2p = fmaf(q0.x,q0.x,e2p); e2p = fmaf(q0.y,q0.y,e2p);
        e2p = fmaf(q0.z,q0.z,e2p); e2p = fmaf(q0.w,q0.w,e2p);
        e2p = fmaf(q1.x,q1.x,e2p); e2p = fmaf(q1.y,q1.y,e2p);
        e2p = fmaf(q1.z,q1.z,e2p); e2p = fmaf(q1.w,q1.w,e2p);
        uint4 ai;
        ai.x = pk2(q0.x, q0.y); ai.y = pk2(q0.z, q0.w);
        ai.z = pk2(q1.x, q1.y); ai.w = pk2(q1.z, q1.w);
        s16x8 av = *reinterpret_cast<s16x8*>(&ai);
        // prefetch next E chunk (in flight across all 16 MFMAs below)
        if (ch + 1 < NCH) {
            const float* ep = Ep + (ch + 1)*32;
            q0 = *reinterpret_cast<const float4*>(ep);
            q1 = *reinterpret_cast<const float4*>(ep + 4);
        }
        const short* cp = Cb + (size_t)ch*8192;
#pragma unroll
        for (int g4 = 0; g4 < 4; ++g4) {
            s16x8 b0 = *reinterpret_cast<const s16x8*>(cp + (g4*4+0)*512);
            s16x8 b1 = *reinterpret_cast<const s16x8*>(cp + (g4*4+1)*512);
            s16x8 b2 = *reinterpret_cast<const s16x8*>(cp + (g4*4+2)*512);
            s16x8 b3 = *reinterpret_cast<const s16x8*>(cp + (g4*4+3)*512);
            acc[g4*4+0] = __builtin_amdgcn_mfma_f32_16x16x32_bf16(av, b0, acc[g4*4+0], 0, 0, 0);
            acc[g4*4+1] = __builtin_amdgcn_mfma_f32_16x16x32_bf16(av, b1, acc[g4*4+1], 0, 0, 0);
            acc[g4*4+2] = __builtin_amdgcn_mfma_f32_16x16x32_bf16(av, b2, acc[g4*4+2], 0, 0, 0);
            acc[g4*4+3] = __builtin_amdgcn_mfma_f32_16x16x32_bf16(av, b3, acc[g4*4+3], 0, 0, 0);
        }
    }

    // ---- e2: lane holds k-partial of row c4; reduce across k-octets (sgr) ----
    float e2f = e2p;
    e2f += __shfl_xor(e2f, 16, 64);
    e2f += __shfl_xor(e2f, 32, 64);
    // output row of C/D frag is sgr*4+g -> fetch that row's e2 from lane (sgr*4+g)
    float e2row[4];
#pragma unroll
    for (int g = 0; g < 4; ++g) e2row[g] = __shfl(e2f, sgr*4 + g, 64);
    float c2v[16];
#pragma unroll
    for (int n = 0; n < 16; ++n) c2v[n] = c2f[n*16 + c4];

    // dot -> dist (C/D: col=lane&15 -> centroid, row=(lane>>4)*4+g -> E row)
#pragma unroll
    for (int n = 0; n < 16; ++n) {
        f32x4 v = acc[n];
#pragma unroll
        for (int g = 0; g < 4; ++g) {
            float d2 = fmaf(-2.f, v[g], e2row[g] + c2v[n]);
            v[g] = sqrtf(fmaxf(d2, 0.f));
        }
        acc[n] = v;
    }

    // ---- top-3 per row over all 256 cols (wave-local) ----
#pragma unroll
    for (int g = 0; g < 4; ++g) {
        float v1 = FLT_MAX, v2 = FLT_MAX;
        int i1 = 0x7fffffff, i2 = 0x7fffffff;
#pragma unroll
        for (int n = 0; n < 16; ++n) {
            float d = acc[n][g];
            int idx = n*16 + c4;
            if (d < v1)      { v2 = v1; i2 = i1; v1 = d; i1 = idx; }
            else if (d < v2) { v2 = d; i2 = idx; }
        }
#pragma unroll
        for (int msk = 1; msk < 16; msk <<= 1) {
            float b1 = __shfl_xor(v1, msk, 64); int bi1 = __shfl_xor(i1, msk, 64);
            float b2 = __shfl_xor(v2, msk, 64); int bi2 = __shfl_xor(i2, msk, 64);
            bool afirst = (v1 < b1) || (v1 == b1 && i1 < bi1);
            float n1, n2; int ni1, ni2;
            if (afirst) {
                n1 = v1; ni1 = i1;
                bool s = (v2 < b1) || (v2 == b1 && i2 < bi1);
                n2 = s ? v2 : b1; ni2 = s ? i2 : bi1;
            } else {
                n1 = b1; ni1 = bi1;
                bool s = (b2 < v1) || (b2 == v1 && bi2 < i1);
                n2 = s ? b2 : v1; ni2 = s ? bi2 : i1;
            }
            v1 = n1; i1 = ni1; v2 = n2; i2 = ni2;
        }
        // masked third pass (v1,i1,v2,i2 now uniform within the 16-lane group)
        float v3 = FLT_MAX; int i3 = 0x7fffffff;
#pragma unroll
        for (int n = 0; n < 16; ++n) {
            float d = acc[n][g];
            int idx = n*16 + c4;
            bool ex = (idx == i1) || (idx == i2);
            if (!ex && d < v3) { v3 = d; i3 = idx; }
        }
#pragma unroll
        for (int msk = 1; msk < 16; msk <<= 1) {
            float ov = __shfl_xor(v3, msk, 64); int oi = __shfl_xor(i3, msk, 64);
            bool take = (ov < v3) || (ov == v3 && oi < i3);
            v3 = take ? ov : v3; i3 = take ? oi : i3;
        }
        if (c4 == 0) {
            int row = R0 + sgr*4 + g;
            labels[row] = (float)i1;
            if (v2 - v1 < MARGIN) {
                int slot = atomicAdd(fix_cnt, 1);
                if (slot < MAXFIX) {
                    fix_list[slot*4+0] = row;
                    fix_list[slot*4+1] = i1;
                    fix_list[slot*4+2] = i2;
                    fix_list[slot*4+3] = i3;
                }
            }
        }
    }

    // ---- per-centroid softmin partials over this wave's 16 rows ----
#pragma unroll
    for (int n = 0; n < 16; ++n) {
        float m0 = fminf(fminf(acc[n][0], acc[n][1]), fminf(acc[n][2], acc[n][3]));
        float s1 = 0.f, s2 = 0.f;
#pragma unroll
        for (int g = 0; g < 4; ++g) {
            float d = acc[n][g];
            float e = expf(m0 - d);
            s1 += e; s2 = fmaf(d, e, s2);
        }
#pragma unroll
        for (int msk = 16; msk < 64; msk <<= 1) {
            float om = __shfl_xor(m0, msk, 64);
            float oa = __shfl_xor(s1, msk, 64);
            float ob = __shfl_xor(s2, msk, 64);
            float Mn = fminf(m0, om);
            float sa = expf(Mn - m0), sb = expf(Mn - om);
            s1 = s1*sa + oa*sb;
            s2 = s2*sa + ob*sb;
            m0 = Mn;
        }
        if (lane < 16) {
            int cc = n*16 + c4;
            spart[w][cc][0] = m0; spart[w][cc][1] = s1; spart[w][cc][2] = s2;
        }
    }
    __syncthreads();
    {   // one thread per centroid merges the 4 wave partials
        int cc = t;
        float M = spart[0][cc][0], A = spart[0][cc][1], Bv = spart[0][cc][2];
#pragma unroll
        for (int i = 1; i < 4; ++i) {
            float om = spart[i][cc][0], oa = spart[i][cc][1], ob = spart[i][cc][2];
            float Mn = fminf(M, om);
            float sa = expf(Mn - M), sb = expf(Mn - om);
            A = A*sa + oa*sb; Bv = Bv*sa + ob*sb; M = Mn;
        }
        float* p = &partials[((size_t)blockIdx.x*K_C + cc)*3];
        p[0] = M; p[1] = A; p[2] = Bv;
    }
}

// ---------------- f64 exact compare of flagged top-3 ----------------
__global__ __launch_bounds__(256) void krefB(const float* __restrict__ E,
    const float* __restrict__ C, const int* __restrict__ fix_cnt,
    const int* __restrict__ fix_list, float* __restrict__ labels)
{
    int cnt = *fix_cnt; if (cnt > MAXFIX) cnt = MAXFIX;
    int lane = threadIdx.x & 63;
    int wv = (int)((blockIdx.x * blockDim.x + threadIdx.x) >> 6);
    const int NW = (gridDim.x * blockDim.x) >> 6;
    for (int e = wv; e < cnt; e += NW) {
        int row = fix_list[e*4+0];
        int k1  = fix_list[e*4+1], k2 = fix_list[e*4+2], k3 = fix_list[e*4+3];
        double s1 = 0, s2 = 0, s3 = 0;
        for (int d = lane; d < D_DIM; d += 64) {
            double ed = (double)E[(size_t)row*D_DIM + d];
            double ca = (double)C[(size_t)k1*D_DIM + d];
            double cb = (double)C[(size_t)k2*D_DIM + d];
            double cc = (double)C[(size_t)k3*D_DIM + d];
            s1 += ca*(ca - 2.0*ed);     // c^2 - 2ec ; e^2 cancels in compare
            s2 += cb*(cb - 2.0*ed);
            s3 += cc*(cc - 2.0*ed);
        }
#pragma unroll
        for (int msk = 32; msk; msk >>= 1) {
            s1 += __shfl_down(s1, msk, 64);
            s2 += __shfl_down(s2, msk, 64);
            s3 += __shfl_down(s3, msk, 64);
        }
        if (lane == 0) {
            double bv = s1; int bk = k1;
            if (s2 < bv || (s2 == bv && k2 < bk)) { bv = s2; bk = k2; }
            if (s3 < bv || (s3 == bv && k3 < bk)) { bv = s3; bk = k3; }
            labels[row] = (float)bk;
        }
    }
}

// ---------------- per-centroid global combine ----------------
__global__ __launch_bounds__(256) void kcol(const float* __restrict__ partials,
                                            float* __restrict__ colloss, int NB)
{
    __shared__ float Wm[4], Wa[4], Wb[4];
    const int c = blockIdx.x;
    const int t = threadIdx.x;
    float M = FLT_MAX, A = 0.f, Bv = 0.f;
    for (int b = t; b < NB; b += 256) {
        const float* p = &partials[((size_t)b*K_C + c)*3];
        float om = p[0], oa = p[1], ob = p[2];
        float Mn = fminf(M, om);
        float sa = expf(Mn - M), sb = expf(Mn - om);
        A = A*sa + oa*sb; Bv = Bv*sa + ob*sb; M = Mn;
    }
    for (int msk = 1; msk < 64; msk <<= 1) {
        float om = __shfl_xor(M, msk, 64);
        float oa = __shfl_xor(A, msk, 64);
        float ob = __shfl_xor(Bv, msk, 64);
        float Mn = fminf(M, om);
        float sa = expf(Mn - M), sb = expf(Mn - om);
        A = A*sa + oa*sb; Bv = Bv*sa + ob*sb; M = Mn;
    }
    int lane = t & 63, wv = t >> 6;
    if (lane == 0) { Wm[wv] = M; Wa[wv] = A; Wb[wv] = Bv; }
    __syncthreads();
    if (t == 0) {
#pragma unroll
        for (int i = 1; i < 4; ++i) {
            float om = Wm[i], oa = Wa[i], ob = Wb[i];
            float Mn = fminf(M, om);
            float sa = expf(Mn - M), sb = expf(Mn - om);
            A = A*sa + oa*sb; Bv = Bv*sa + ob*sb; M = Mn;
        }
        colloss[c] = Bv / A;
    }
}

// ---------------- final mean over centroids ----------------
__global__ __launch_bounds__(256) void kfinal(const float* __restrict__ colloss,
                                              float* __restrict__ out)
{
    __shared__ float Ws[4];
    int t = threadIdx.x;
    float v = colloss[t];
    for (int msk = 1; msk < 64; msk <<= 1) v += __shfl_xor(v, msk, 64);
    if ((t & 63) == 0) Ws[t >> 6] = v;
    __syncthreads();
    if (t == 0) out[0] = (Ws[0] + Ws[1] + Ws[2] + Ws[3]) / 256.0f;
}

extern "C" void kernel_launch(void* const* d_in, const int* in_sizes, int n_in,
                              void* d_out, int out_size, void* d_ws, size_t ws_size,
                              hipStream_t stream)
{
    const float* E = (const float*)d_in[0];
    const float* C = (const float*)d_in[1];
    float* out = (float*)d_out;

    const int Bn = in_sizes[0] / D_DIM;      // 65536
    const int NB = Bn / 64;                  // 1024 blocks (4 waves x 16 rows)

    char* ws = (char*)d_ws;
    float* c2f      = (float*)ws;                                  // 1 KB
    int*   fix_cnt  = (int*)(ws + 1024);
    int*   fix_list = (int*)(ws + 1088);                           // MAXFIX*16
    short* Cimg     = (short*)(ws + 1088 + MAXFIX*16);             // 384 KB
    float* partials = (float*)((char*)Cimg + (size_t)NCH*16384);   // NB*256*3*4 = 3 MB
    float* colloss  = partials + (size_t)NB*K_C*3;
    float* labels   = out + 1;

    kprep <<<K_C, 256, 0, stream>>>(C, Cimg, c2f, fix_cnt);
    kdist <<<NB,  256, 0, stream>>>(E, Cimg, c2f, labels, partials,
                                    fix_cnt, fix_list);
    krefB <<<128, 256, 0, stream>>>(E, C, fix_cnt, fix_list, labels);
    kcol  <<<K_C, 256, 0, stream>>>(partials, colloss, NB);
    kfinal<<<1,   256, 0, stream>>>(colloss, out);
}

// Round 8
// 113.585 us; speedup vs baseline: 1.7968x; 1.7968x over previous
//
#include <hip/hip_runtime.h>
#include <math.h>
#include <float.h>

#define D_DIM 768
#define K_C   256
#define KC    32
#define NCH   24
#define BMR   64
#define MAXFIX 32768
#define MARGIN 1.5e-2f

typedef __attribute__((ext_vector_type(8))) short s16x8;
typedef __attribute__((ext_vector_type(4))) float f32x4;

__device__ inline unsigned short f2bf(float x) {      // RNE f32 -> bf16 bits
    unsigned u = __float_as_uint(x);
    unsigned r = 0x7FFFu + ((u >> 16) & 1u);
    return (unsigned short)((u + r) >> 16);
}
// swizzled elem offset into a [rows][32]-short tile; 16B granule slot 0..3
__device__ inline int swz(int row, int slot) {
    return row*32 + (((slot ^ (row >> 1)) & 3) << 3);
}
__device__ inline void gl_lds16(const void* g, void* l) {
    __builtin_amdgcn_global_load_lds(
        (const __attribute__((address_space(1))) void*)g,
        (__attribute__((address_space(3))) void*)l, 16, 0, 0);
}
// pack trunc-bf16 of (a,b) -> u32 {lo16=hi(a), hi16=hi(b)} via v_perm
__device__ inline unsigned pk2(float a, float b) {
    return __builtin_amdgcn_perm(__float_as_uint(b), __float_as_uint(a), 0x07060302u);
}

// ---------------- prep: c2 (f64) + C -> per-chunk swizzled bf16 image ----------------
__global__ __launch_bounds__(256) void kprep(const float* __restrict__ C,
    short* __restrict__ Cimg, float* __restrict__ c2f, int* __restrict__ fix_cnt)
{
    const int k = blockIdx.x;       // centroid
    const int t = threadIdx.x;
    __shared__ double red[4];
    double s = 0.0;
#pragma unroll
    for (int i = 0; i < 3; ++i) {
        int d = t + 256*i;
        float x = C[(size_t)k*D_DIM + d];
        s += (double)x * (double)x;
        int ch = d >> 5, g = (d & 31) >> 3, e = d & 7;
        Cimg[(size_t)ch*8192 + swz(k, g) + e] = (short)f2bf(x);
    }
#pragma unroll
    for (int m = 1; m < 64; m <<= 1) s += __shfl_xor(s, m, 64);
    if ((t & 63) == 0) red[t >> 6] = s;
    __syncthreads();
    if (t == 0) {
        c2f[k] = (float)(red[0] + red[1] + red[2] + red[3]);
        if (k == 0) *fix_cnt = 0;
    }
}

// ---------------- main fused MFMA kernel: 64 rows x 256 cols, 4 waves ----------------
// 40KB LDS -> 4 blocks/CU -> 16 waves/CU from 4 independent barrier groups.
__global__ __launch_bounds__(256, 4) void kdist(const float* __restrict__ E,
    const short* __restrict__ Cimg, const float* __restrict__ c2f,
    float* __restrict__ labels, float* __restrict__ partials,
    int* __restrict__ fix_cnt, int* __restrict__ fix_list)
{
    __shared__ __align__(16) char lds[40960];
    // Eb0 @0 (4KB), Eb1 @4096, Cb0 @8192 (16KB), Cb1 @24576
    // epilogue overlay (valid after final loop barrier):
    float*  e2s   = (float*)lds;                     // [64]
    float*  spart = (float*)(lds + 256);             // [2][256][3]  6KB
    float4* topb  = (float4*)(lds + 256 + 6144);     // [(wn*64+row)*2+{0,1}] 4KB

    const int t    = threadIdx.x;
    const int lane = t & 63;
    const int w    = t >> 6;
    const int wm   = w >> 1, wn = w & 1;             // row-half / col-half
    const int c4   = lane & 15, sgr = lane >> 4;
    const int R0   = blockIdx.x * BMR;

    f32x4 acc[2][8];
#pragma unroll
    for (int m = 0; m < 2; ++m)
#pragma unroll
        for (int n = 0; n < 8; ++n) acc[m][n] = (f32x4){0.f,0.f,0.f,0.f};

    // E staging: 4 threads/row, 8 f32 each -> one 16B swizzled granule
    const int erow = t >> 2, eseg = t & 3;
    const float* Ep = E + (size_t)(R0 + erow)*D_DIM + eseg*8;
    const int ebyte = 2*swz(erow, eseg);

    const int aoff0 = 2*swz(wm*32 + 0*16 + c4, sgr);
    const int aoff1 = 2*swz(wm*32 + 1*16 + c4, sgr);
    int boff[8];
#pragma unroll
    for (int n = 0; n < 8; ++n) boff[n] = 2*swz(wn*128 + n*16 + c4, sgr);

    float e2p = 0.f;
    float4 q0, q1;

#define ECONV(EBASE) do {                                               \
        e2p = fmaf(q0.x,q0.x,e2p); e2p = fmaf(q0.y,q0.y,e2p);           \
        e2p = fmaf(q0.z,q0.z,e2p); e2p = fmaf(q0.w,q0.w,e2p);           \
        e2p = fmaf(q1.x,q1.x,e2p); e2p = fmaf(q1.y,q1.y,e2p);           \
        e2p = fmaf(q1.z,q1.z,e2p); e2p = fmaf(q1.w,q1.w,e2p);           \
        uint4 Ha;                                                       \
        Ha.x = pk2(q0.x,q0.y); Ha.y = pk2(q0.z,q0.w);                   \
        Ha.z = pk2(q1.x,q1.y); Ha.w = pk2(q1.z,q1.w);                   \
        *reinterpret_cast<uint4*>((EBASE) + ebyte) = Ha;                \
    } while (0)

    // ---- prologue: C(0)->Cb0, E(0)->Eb0, E(1)->regs ----
    {
        const char* img0 = (const char*)Cimg;
#pragma unroll
        for (int j = 0; j < 4; ++j)
            gl_lds16(img0 + j*4096 + t*16, lds + 8192 + j*4096 + t*16);
        q0 = *reinterpret_cast<const float4*>(Ep);
        q1 = *reinterpret_cast<const float4*>(Ep + 4);
        ECONV(lds);
        q0 = *reinterpret_cast<const float4*>(Ep + KC);
        q1 = *reinterpret_cast<const float4*>(Ep + KC + 4);
    }
    __syncthreads();

    for (int ch = 0; ch < NCH; ++ch) {
        char* ecur = lds + ((ch & 1) << 12);
        char* enxt = lds + ((~ch & 1) << 12);
        char* ccur = lds + 8192 + ((ch & 1) << 14);
        char* cnxt = lds + 8192 + ((~ch & 1) << 14);
        if (ch + 1 < NCH) {
            const char* img = (const char*)Cimg + (size_t)(ch + 1)*16384;
#pragma unroll
            for (int j = 0; j < 4; ++j)
                gl_lds16(img + j*4096 + t*16, cnxt + j*4096 + t*16);
            ECONV(enxt);                        // E(ch+1) from q regs
            if (ch + 2 < NCH) {                 // reload q with E(ch+2)
                const float* ep = Ep + (ch + 2)*KC;
                q0 = *reinterpret_cast<const float4*>(ep);
                q1 = *reinterpret_cast<const float4*>(ep + 4);
            }
        }
        s16x8 ah0 = *reinterpret_cast<const s16x8*>(ecur + aoff0);
        s16x8 ah1 = *reinterpret_cast<const s16x8*>(ecur + aoff1);
#pragma unroll
        for (int n = 0; n < 8; ++n) {
            s16x8 bh = *reinterpret_cast<const s16x8*>(ccur + boff[n]);
            acc[0][n] = __builtin_amdgcn_mfma_f32_16x16x32_bf16(ah0, bh, acc[0][n], 0, 0, 0);
            acc[1][n] = __builtin_amdgcn_mfma_f32_16x16x32_bf16(ah1, bh, acc[1][n], 0, 0, 0);
        }
        __syncthreads();
    }
#undef ECONV

    // ---- e2 per row (4 threads/row) ----
    {
        float es = e2p + __shfl_xor(e2p, 1, 64);
        es += __shfl_xor(es, 2, 64);
        if ((t & 3) == 0) e2s[t >> 2] = es;
    }
    __syncthreads();

    float e2r[2][4];
#pragma unroll
    for (int m = 0; m < 2; ++m)
#pragma unroll
        for (int g = 0; g < 4; ++g)
            e2r[m][g] = e2s[wm*32 + m*16 + sgr*4 + g];
    float c2v[8];
#pragma unroll
    for (int n = 0; n < 8; ++n) c2v[n] = c2f[wn*128 + n*16 + c4];

    // dot -> dist (C/D: col=lane&15 -> centroid, row=(lane>>4)*4+g -> E row)
#pragma unroll
    for (int m = 0; m < 2; ++m)
#pragma unroll
        for (int n = 0; n < 8; ++n) {
            f32x4 v = acc[m][n];
#pragma unroll
            for (int g = 0; g < 4; ++g) {
                float d2 = fmaf(-2.f, v[g], e2r[m][g] + c2v[n]);
                v[g] = sqrtf(fmaxf(d2, 0.f));
            }
            acc[m][n] = v;
        }

    // ---- top-3 per row over this wave's 128 cols ----
#pragma unroll
    for (int m = 0; m < 2; ++m)
#pragma unroll
        for (int g = 0; g < 4; ++g) {
            float v1 = FLT_MAX, v2 = FLT_MAX;
            int i1 = 0x7fffffff, i2 = 0x7fffffff;
#pragma unroll
            for (int n = 0; n < 8; ++n) {
                float d = acc[m][n][g];
                int idx = wn*128 + n*16 + c4;
                if (d < v1)      { v2 = v1; i2 = i1; v1 = d; i1 = idx; }
                else if (d < v2) { v2 = d; i2 = idx; }
            }
#pragma unroll
            for (int msk = 1; msk < 16; msk <<= 1) {
                float b1 = __shfl_xor(v1, msk, 64); int bi1 = __shfl_xor(i1, msk, 64);
                float b2 = __shfl_xor(v2, msk, 64); int bi2 = __shfl_xor(i2, msk, 64);
                bool afirst = (v1 < b1) || (v1 == b1 && i1 < bi1);
                float n1, n2; int ni1, ni2;
                if (afirst) {
                    n1 = v1; ni1 = i1;
                    bool s = (v2 < b1) || (v2 == b1 && i2 < bi1);
                    n2 = s ? v2 : b1; ni2 = s ? i2 : bi1;
                } else {
                    n1 = b1; ni1 = bi1;
                    bool s = (b2 < v1) || (b2 == v1 && bi2 < i1);
                    n2 = s ? b2 : v1; ni2 = s ? bi2 : i1;
                }
                v1 = n1; i1 = ni1; v2 = n2; i2 = ni2;
            }
            // masked third (v1,i1,v2,i2 uniform within 16-lane group)
            float v3 = FLT_MAX; int i3 = 0x7fffffff;
#pragma unroll
            for (int n = 0; n < 8; ++n) {
                float d = acc[m][n][g];
                int idx = wn*128 + n*16 + c4;
                bool ex = (idx == i1) || (idx == i2);
                if (!ex && d < v3) { v3 = d; i3 = idx; }
            }
#pragma unroll
            for (int msk = 1; msk < 16; msk <<= 1) {
                float ov = __shfl_xor(v3, msk, 64); int oi = __shfl_xor(i3, msk, 64);
                bool take = (ov < v3) || (ov == v3 && oi < i3);
                v3 = take ? ov : v3; i3 = take ? oi : i3;
            }
            if (c4 == 0) {
                int row = wm*32 + m*16 + sgr*4 + g;
                topb[(size_t)(wn*BMR + row)*2]     = (float4){v1, (float)i1, v2, (float)i2};
                topb[(size_t)(wn*BMR + row)*2 + 1] = (float4){v3, (float)i3, 0.f, 0.f};
            }
        }

    // ---- per-centroid softmin partials over this wave's 32 rows ----
#pragma unroll
    for (int n = 0; n < 8; ++n) {
        float m0 = FLT_MAX;
#pragma unroll
        for (int m = 0; m < 2; ++m)
#pragma unroll
            for (int g = 0; g < 4; ++g) m0 = fminf(m0, acc[m][n][g]);
        float s1 = 0.f, s2 = 0.f;
#pragma unroll
        for (int m = 0; m < 2; ++m)
#pragma unroll
            for (int g = 0; g < 4; ++g) {
                float d = acc[m][n][g];
                float e = expf(m0 - d);
                s1 += e; s2 = fmaf(d, e, s2);
            }
#pragma unroll
        for (int msk = 16; msk < 64; msk <<= 1) {
            float om = __shfl_xor(m0, msk, 64);
            float oa = __shfl_xor(s1, msk, 64);
            float ob = __shfl_xor(s2, msk, 64);
            float Mn = fminf(m0, om);
            float sa = expf(Mn - m0), sb = expf(Mn - om);
            s1 = s1*sa + oa*sb;
            s2 = s2*sa + ob*sb;
            m0 = Mn;
        }
        if (lane < 16) {
            int cc = wn*128 + n*16 + c4;
            float* p = &spart[((size_t)wm*K_C + cc)*3];
            p[0] = m0; p[1] = s1; p[2] = s2;
        }
    }
    __syncthreads();

    if (t < BMR) {
        float4 a0 = topb[(size_t)t*2],        a1 = topb[(size_t)t*2 + 1];
        float4 b0 = topb[(size_t)(BMR+t)*2],  b1 = topb[(size_t)(BMR+t)*2 + 1];
        float v1 = a0.x, v2 = a0.z, v3 = a1.x;
        int   i1 = (int)a0.y, i2 = (int)a0.w, i3 = (int)a1.y;
#define T3INS(DV, DI) do { float d_ = (DV); int id_ = (DI);             \
        bool b3 = d_ < v3, b2 = d_ < v2, b1c = d_ < v1;                 \
        float nv3 = b2 ? v2 : (b3 ? d_ : v3);                           \
        int   ni3 = b2 ? i2 : (b3 ? id_ : i3);                          \
        float nv2 = b1c ? v1 : (b2 ? d_ : v2);                          \
        int   ni2 = b1c ? i1 : (b2 ? id_ : i2);                         \
        v1 = b1c ? d_ : v1; i1 = b1c ? id_ : i1;                        \
        v2 = nv2; i2 = ni2; v3 = nv3; i3 = ni3; } while (0)
        T3INS(b0.x, (int)b0.y);
        T3INS(b0.z, (int)b0.w);
        T3INS(b1.x, (int)b1.y);
#undef T3INS
        int row = R0 + t;
        labels[row] = (float)i1;
        if (v2 - v1 < MARGIN) {
            int slot = atomicAdd(fix_cnt, 1);
            if (slot < MAXFIX) {
                fix_list[slot*4+0] = row;
                fix_list[slot*4+1] = i1;
                fix_list[slot*4+2] = i2;
                fix_list[slot*4+3] = i3;
            }
        }
    }
    {
        int cc = t;
        const float* p0 = &spart[(size_t)cc*3];
        const float* p1 = &spart[((size_t)K_C + cc)*3];
        float M = p0[0], A = p0[1], Bv = p0[2];
        float om = p1[0], oa = p1[1], ob = p1[2];
        float Mn = fminf(M, om);
        float sa = expf(Mn - M), sb = expf(Mn - om);
        A = A*sa + oa*sb; Bv = Bv*sa + ob*sb;
        float* p = &partials[((size_t)blockIdx.x*K_C + cc)*3];
        p[0] = Mn; p[1] = A; p[2] = Bv;
    }
}

// ---------------- f64 exact compare of flagged top-3 ----------------
__global__ __launch_bounds__(256) void krefB(const float* __restrict__ E,
    const float* __restrict__ C, const int* __restrict__ fix_cnt,
    const int* __restrict__ fix_list, float* __restrict__ labels)
{
    int cnt = *fix_cnt; if (cnt > MAXFIX) cnt = MAXFIX;
    int lane = threadIdx.x & 63;
    int wv = (int)((blockIdx.x * blockDim.x + threadIdx.x) >> 6);
    const int NW = (gridDim.x * blockDim.x) >> 6;
    for (int e = wv; e < cnt; e += NW) {
        int row = fix_list[e*4+0];
        int k1  = fix_list[e*4+1], k2 = fix_list[e*4+2], k3 = fix_list[e*4+3];
        double s1 = 0, s2 = 0, s3 = 0;
        for (int d = lane; d < D_DIM; d += 64) {
            double ed = (double)E[(size_t)row*D_DIM + d];
            double ca = (double)C[(size_t)k1*D_DIM + d];
            double cb = (double)C[(size_t)k2*D_DIM + d];
            double cc = (double)C[(size_t)k3*D_DIM + d];
            s1 += ca*(ca - 2.0*ed);     // c^2 - 2ec ; e^2 cancels in compare
            s2 += cb*(cb - 2.0*ed);
            s3 += cc*(cc - 2.0*ed);
        }
#pragma unroll
        for (int msk = 32; msk; msk >>= 1) {
            s1 += __shfl_down(s1, msk, 64);
            s2 += __shfl_down(s2, msk, 64);
            s3 += __shfl_down(s3, msk, 64);
        }
        if (lane == 0) {
            double bv = s1; int bk = k1;
            if (s2 < bv || (s2 == bv && k2 < bk)) { bv = s2; bk = k2; }
            if (s3 < bv || (s3 == bv && k3 < bk)) { bv = s3; bk = k3; }
            labels[row] = (float)bk;
        }
    }
}

// ---------------- per-centroid global combine ----------------
__global__ __launch_bounds__(256) void kcol(const float* __restrict__ partials,
                                            float* __restrict__ colloss, int NB)
{
    __shared__ float Wm[4], Wa[4], Wb[4];
    const int c = blockIdx.x;
    const int t = threadIdx.x;
    float M = FLT_MAX, A = 0.f, Bv = 0.f;
    for (int b = t; b < NB; b += 256) {
        const float* p = &partials[((size_t)b*K_C + c)*3];
        float om = p[0], oa = p[1], ob = p[2];
        float Mn = fminf(M, om);
        float sa = expf(Mn - M), sb = expf(Mn - om);
        A = A*sa + oa*sb; Bv = Bv*sa + ob*sb; M = Mn;
    }
    for (int msk = 1; msk < 64; msk <<= 1) {
        float om = __shfl_xor(M, msk, 64);
        float oa = __shfl_xor(A, msk, 64);
        float ob = __shfl_xor(Bv, msk, 64);
        float Mn = fminf(M, om);
        float sa = expf(Mn - M), sb = expf(Mn - om);
        A = A*sa + oa*sb; Bv = Bv*sa + ob*sb; M = Mn;
    }
    int lane = t & 63, wv = t >> 6;
    if (lane == 0) { Wm[wv] = M; Wa[wv] = A; Wb[wv] = Bv; }
    __syncthreads();
    if (t == 0) {
#pragma unroll
        for (int i = 1; i < 4; ++i) {
            float om = Wm[i], oa = Wa[i], ob = Wb[i];
            float Mn = fminf(M, om);
            float sa = expf(Mn - M), sb = expf(Mn - om);
            A = A*sa + oa*sb; Bv = Bv*sa + ob*sb; M = Mn;
        }
        colloss[c] = Bv / A;
    }
}

// ---------------- final mean over centroids ----------------
__global__ __launch_bounds__(256) void kfinal(const float* __restrict__ colloss,
                                              float* __restrict__ out)
{
    __shared__ float Ws[4];
    int t = threadIdx.x;
    float v = colloss[t];
    for (int msk = 1; msk < 64; msk <<= 1) v += __shfl_xor(v, msk, 64);
    if ((t & 63) == 0) Ws[t >> 6] = v;
    __syncthreads();
    if (t == 0) out[0] = (Ws[0] + Ws[1] + Ws[2] + Ws[3]) / 256.0f;
}

extern "C" void kernel_launch(void* const* d_in, const int* in_sizes, int n_in,
                              void* d_out, int out_size, void* d_ws, size_t ws_size,
                              hipStream_t stream)
{
    const float* E = (const float*)d_in[0];
    const float* C = (const float*)d_in[1];
    float* out = (float*)d_out;

    const int Bn = in_sizes[0] / D_DIM;      // 65536
    const int NB = Bn / BMR;                 // 1024

    char* ws = (char*)d_ws;
    float* c2f      = (float*)ws;                                  // 1 KB
    int*   fix_cnt  = (int*)(ws + 1024);
    int*   fix_list = (int*)(ws + 1088);                           // MAXFIX*16
    short* Cimg     = (short*)(ws + 1088 + MAXFIX*16);             // 384 KB
    float* partials = (float*)((char*)Cimg + (size_t)NCH*16384);   // NB*256*3*4 = 3 MB
    float* colloss  = partials + (size_t)NB*K_C*3;
    float* labels   = out + 1;

    kprep <<<K_C, 256, 0, stream>>>(C, Cimg, c2f, fix_cnt);
    kdist <<<NB,  256, 0, stream>>>(E, Cimg, c2f, labels, partials,
                                    fix_cnt, fix_list);
    krefB <<<128, 256, 0, stream>>>(E, C, fix_cnt, fix_list, labels);
    kcol  <<<K_C, 256, 0, stream>>>(partials, colloss, NB);
    kfinal<<<1,   256, 0, stream>>>(colloss, out);
}

// Round 9
// 113.053 us; speedup vs baseline: 1.8053x; 1.0047x over previous
//
#include <hip/hip_runtime.h>
#include <math.h>
#include <float.h>

#define D_DIM 768
#define K_C   256
#define KC    32
#define NCH   24
#define BMR   64
#define MAXFIX 32768
#define MARGIN 1.5e-2f

typedef __attribute__((ext_vector_type(8))) short s16x8;
typedef __attribute__((ext_vector_type(4))) float f32x4;

__device__ inline unsigned short f2bf(float x) {      // RNE f32 -> bf16 bits
    unsigned u = __float_as_uint(x);
    unsigned r = 0x7FFFu + ((u >> 16) & 1u);
    return (unsigned short)((u + r) >> 16);
}
// swizzled elem offset into a [rows][32]-short tile; 16B granule slot 0..3
__device__ inline int swz(int row, int slot) {
    return row*32 + (((slot ^ (row >> 1)) & 3) << 3);
}
__device__ inline void gl_lds16(const void* g, void* l) {
    __builtin_amdgcn_global_load_lds(
        (const __attribute__((address_space(1))) void*)g,
        (__attribute__((address_space(3))) void*)l, 16, 0, 0);
}
// pack trunc-bf16 of (a,b) -> u32 {lo16=hi(a), hi16=hi(b)} via v_perm
__device__ inline unsigned pk2(float a, float b) {
    return __builtin_amdgcn_perm(__float_as_uint(b), __float_as_uint(a), 0x07060302u);
}

// ---------------- prep: c2 (f64) + C -> per-chunk swizzled bf16 image ----------------
__global__ __launch_bounds__(256) void kprep(const float* __restrict__ C,
    short* __restrict__ Cimg, float* __restrict__ c2f, int* __restrict__ fix_cnt)
{
    const int k = blockIdx.x;       // centroid
    const int t = threadIdx.x;
    __shared__ double red[4];
    double s = 0.0;
#pragma unroll
    for (int i = 0; i < 3; ++i) {
        int d = t + 256*i;
        float x = C[(size_t)k*D_DIM + d];
        s += (double)x * (double)x;
        int ch = d >> 5, g = (d & 31) >> 3, e = d & 7;
        Cimg[(size_t)ch*8192 + swz(k, g) + e] = (short)f2bf(x);
    }
#pragma unroll
    for (int m = 1; m < 64; m <<= 1) s += __shfl_xor(s, m, 64);
    if ((t & 63) == 0) red[t >> 6] = s;
    __syncthreads();
    if (t == 0) {
        c2f[k] = (float)(red[0] + red[1] + red[2] + red[3]);
        if (k == 0) *fix_cnt = 0;
    }
}

// ---------------- main fused MFMA kernel: 64 rows x 256 cols, 4 waves ----------------
// 40KB LDS -> 4 blocks/CU. Counted-vmcnt pipeline: never drain vmcnt(0) in loop.
__global__ __launch_bounds__(256, 4) void kdist(const float* __restrict__ E,
    const short* __restrict__ Cimg, const float* __restrict__ c2f,
    float* __restrict__ labels, float* __restrict__ partials,
    int* __restrict__ fix_cnt, int* __restrict__ fix_list)
{
    __shared__ __align__(16) char lds[40960];
    // Eb0 @0 (4KB), Eb1 @4096, Cb0 @8192 (16KB), Cb1 @24576
    // epilogue overlay (valid after final __syncthreads):
    float*  e2s   = (float*)lds;                     // [64]
    float*  spart = (float*)(lds + 256);             // [2][256][3]  6KB
    float4* topb  = (float4*)(lds + 256 + 6144);     // [(wn*64+row)*2+{0,1}] 4KB

    const int t    = threadIdx.x;
    const int lane = t & 63;
    const int w    = t >> 6;
    const int wm   = w >> 1, wn = w & 1;             // row-half / col-half
    const int c4   = lane & 15, sgr = lane >> 4;
    const int R0   = blockIdx.x * BMR;

    f32x4 acc[2][8];
#pragma unroll
    for (int m = 0; m < 2; ++m)
#pragma unroll
        for (int n = 0; n < 8; ++n) acc[m][n] = (f32x4){0.f,0.f,0.f,0.f};

    // E staging: 4 threads/row, 8 f32 each -> one 16B swizzled granule
    const int erow = t >> 2, eseg = t & 3;
    const float* Ep = E + (size_t)(R0 + erow)*D_DIM + eseg*8;
    const int ebyte = 2*swz(erow, eseg);

    const int aoff0 = 2*swz(wm*32 + 0*16 + c4, sgr);
    const int aoff1 = 2*swz(wm*32 + 1*16 + c4, sgr);
    int boff[8];
#pragma unroll
    for (int n = 0; n < 8; ++n) boff[n] = 2*swz(wn*128 + n*16 + c4, sgr);

    float e2p = 0.f;
    float4 q0, q1;

#define ECONV(EBASE) do {                                               \
        e2p = fmaf(q0.x,q0.x,e2p); e2p = fmaf(q0.y,q0.y,e2p);           \
        e2p = fmaf(q0.z,q0.z,e2p); e2p = fmaf(q0.w,q0.w,e2p);           \
        e2p = fmaf(q1.x,q1.x,e2p); e2p = fmaf(q1.y,q1.y,e2p);           \
        e2p = fmaf(q1.z,q1.z,e2p); e2p = fmaf(q1.w,q1.w,e2p);           \
        uint4 Ha;                                                       \
        Ha.x = pk2(q0.x,q0.y); Ha.y = pk2(q0.z,q0.w);                   \
        Ha.z = pk2(q1.x,q1.y); Ha.w = pk2(q1.z,q1.w);                   \
        *reinterpret_cast<uint4*>((EBASE) + ebyte) = Ha;                \
    } while (0)

    // ---- prologue: C(0)->Cb0 (drained by ECONV's auto-wait), E(0)->Eb0, E(1)->regs ----
    {
        const char* img0 = (const char*)Cimg;
#pragma unroll
        for (int j = 0; j < 4; ++j)
            gl_lds16(img0 + j*4096 + t*16, lds + 8192 + j*4096 + t*16);
        q0 = *reinterpret_cast<const float4*>(Ep);
        q1 = *reinterpret_cast<const float4*>(Ep + 4);
        ECONV(lds);                 // compiler waits vmcnt for q -> C(0) also lands
        q0 = *reinterpret_cast<const float4*>(Ep + KC);
        q1 = *reinterpret_cast<const float4*>(Ep + KC + 4);
        asm volatile("s_waitcnt lgkmcnt(0)" ::: "memory");
        __builtin_amdgcn_s_barrier();      // outstanding: E(1) x2 only
        __builtin_amdgcn_sched_barrier(0);
    }

    for (int ch = 0; ch < NCH; ++ch) {
        char* ecur = lds + ((ch & 1) << 12);
        char* enxt = lds + ((~ch & 1) << 12);
        char* ccur = lds + 8192 + ((ch & 1) << 14);
        char* cnxt = lds + 8192 + ((~ch & 1) << 14);
        // 1) issue C(ch+1) gl_lds into the buffer freed by the previous barrier
        if (ch + 1 < NCH) {
            const char* img = (const char*)Cimg + (size_t)(ch + 1)*16384;
#pragma unroll
            for (int j = 0; j < 4; ++j)
                gl_lds16(img + j*4096 + t*16, cnxt + j*4096 + t*16);
        }
        __builtin_amdgcn_sched_barrier(0);   // pin order: gl_lds before E loads
        // 2) issue E(ch+2) reg loads (stay in flight across the barrier)
        float4 p0, p1;
        if (ch + 2 < NCH) {
            const float* ep = Ep + (ch + 2)*KC;
            p0 = *reinterpret_cast<const float4*>(ep);
            p1 = *reinterpret_cast<const float4*>(ep + 4);
        }
        // 3) MFMA on current buffers (resident: guaranteed by prev vmcnt+barrier)
        s16x8 ah0 = *reinterpret_cast<const s16x8*>(ecur + aoff0);
        s16x8 ah1 = *reinterpret_cast<const s16x8*>(ecur + aoff1);
#pragma unroll
        for (int n = 0; n < 8; ++n) {
            s16x8 bh = *reinterpret_cast<const s16x8*>(ccur + boff[n]);
            acc[0][n] = __builtin_amdgcn_mfma_f32_16x16x32_bf16(ah0, bh, acc[0][n], 0, 0, 0);
            acc[1][n] = __builtin_amdgcn_mfma_f32_16x16x32_bf16(ah1, bh, acc[1][n], 0, 0, 0);
        }
        // 4) convert E(ch+1) (q regs, loaded one full iteration ago) into next E buf
        if (ch + 1 < NCH) {
            ECONV(enxt);
            q0 = p0; q1 = p1;
        }
        // 5) counted-vmcnt barrier: C(ch+1) landed for all waves; E loads in flight
        if (ch + 2 < NCH) {
            asm volatile("s_waitcnt vmcnt(2) lgkmcnt(0)" ::: "memory");
            __builtin_amdgcn_s_barrier();
            __builtin_amdgcn_sched_barrier(0);
        } else if (ch + 1 < NCH) {
            asm volatile("s_waitcnt vmcnt(0) lgkmcnt(0)" ::: "memory");
            __builtin_amdgcn_s_barrier();
            __builtin_amdgcn_sched_barrier(0);
        } else {
            __syncthreads();                 // full drain before epilogue overlay
        }
    }
#undef ECONV

    // ---- e2 per row (4 threads/row) ----
    {
        float es = e2p + __shfl_xor(e2p, 1, 64);
        es += __shfl_xor(es, 2, 64);
        if ((t & 3) == 0) e2s[t >> 2] = es;
    }
    __syncthreads();

    float e2r[2][4];
#pragma unroll
    for (int m = 0; m < 2; ++m)
#pragma unroll
        for (int g = 0; g < 4; ++g)
            e2r[m][g] = e2s[wm*32 + m*16 + sgr*4 + g];
    float c2v[8];
#pragma unroll
    for (int n = 0; n < 8; ++n) c2v[n] = c2f[wn*128 + n*16 + c4];

    // dot -> dist (C/D: col=lane&15 -> centroid, row=(lane>>4)*4+g -> E row)
#pragma unroll
    for (int m = 0; m < 2; ++m)
#pragma unroll
        for (int n = 0; n < 8; ++n) {
            f32x4 v = acc[m][n];
#pragma unroll
            for (int g = 0; g < 4; ++g) {
                float d2 = fmaf(-2.f, v[g], e2r[m][g] + c2v[n]);
                v[g] = sqrtf(fmaxf(d2, 0.f));
            }
            acc[m][n] = v;
        }

    // ---- top-3 per row over this wave's 128 cols ----
#pragma unroll
    for (int m = 0; m < 2; ++m)
#pragma unroll
        for (int g = 0; g < 4; ++g) {
            float v1 = FLT_MAX, v2 = FLT_MAX;
            int i1 = 0x7fffffff, i2 = 0x7fffffff;
#pragma unroll
            for (int n = 0; n < 8; ++n) {
                float d = acc[m][n][g];
                int idx = wn*128 + n*16 + c4;
                if (d < v1)      { v2 = v1; i2 = i1; v1 = d; i1 = idx; }
                else if (d < v2) { v2 = d; i2 = idx; }
            }
#pragma unroll
            for (int msk = 1; msk < 16; msk <<= 1) {
                float b1 = __shfl_xor(v1, msk, 64); int bi1 = __shfl_xor(i1, msk, 64);
                float b2 = __shfl_xor(v2, msk, 64); int bi2 = __shfl_xor(i2, msk, 64);
                bool afirst = (v1 < b1) || (v1 == b1 && i1 < bi1);
                float n1, n2; int ni1, ni2;
                if (afirst) {
                    n1 = v1; ni1 = i1;
                    bool s = (v2 < b1) || (v2 == b1 && i2 < bi1);
                    n2 = s ? v2 : b1; ni2 = s ? i2 : bi1;
                } else {
                    n1 = b1; ni1 = bi1;
                    bool s = (b2 < v1) || (b2 == v1 && bi2 < i1);
                    n2 = s ? b2 : v1; ni2 = s ? bi2 : i1;
                }
                v1 = n1; i1 = ni1; v2 = n2; i2 = ni2;
            }
            // masked third (v1,i1,v2,i2 uniform within 16-lane group)
            float v3 = FLT_MAX; int i3 = 0x7fffffff;
#pragma unroll
            for (int n = 0; n < 8; ++n) {
                float d = acc[m][n][g];
                int idx = wn*128 + n*16 + c4;
                bool ex = (idx == i1) || (idx == i2);
                if (!ex && d < v3) { v3 = d; i3 = idx; }
            }
#pragma unroll
            for (int msk = 1; msk < 16; msk <<= 1) {
                float ov = __shfl_xor(v3, msk, 64); int oi = __shfl_xor(i3, msk, 64);
                bool take = (ov < v3) || (ov == v3 && oi < i3);
                v3 = take ? ov : v3; i3 = take ? oi : i3;
            }
            if (c4 == 0) {
                int row = wm*32 + m*16 + sgr*4 + g;
                topb[(size_t)(wn*BMR + row)*2]     = (float4){v1, (float)i1, v2, (float)i2};
                topb[(size_t)(wn*BMR + row)*2 + 1] = (float4){v3, (float)i3, 0.f, 0.f};
            }
        }

    // ---- per-centroid softmin partials over this wave's 32 rows ----
#pragma unroll
    for (int n = 0; n < 8; ++n) {
        float m0 = FLT_MAX;
#pragma unroll
        for (int m = 0; m < 2; ++m)
#pragma unroll
            for (int g = 0; g < 4; ++g) m0 = fminf(m0, acc[m][n][g]);
        float s1 = 0.f, s2 = 0.f;
#pragma unroll
        for (int m = 0; m < 2; ++m)
#pragma unroll
            for (int g = 0; g < 4; ++g) {
                float d = acc[m][n][g];
                float e = expf(m0 - d);
                s1 += e; s2 = fmaf(d, e, s2);
            }
#pragma unroll
        for (int msk = 16; msk < 64; msk <<= 1) {
            float om = __shfl_xor(m0, msk, 64);
            float oa = __shfl_xor(s1, msk, 64);
            float ob = __shfl_xor(s2, msk, 64);
            float Mn = fminf(m0, om);
            float sa = expf(Mn - m0), sb = expf(Mn - om);
            s1 = s1*sa + oa*sb;
            s2 = s2*sa + ob*sb;
            m0 = Mn;
        }
        if (lane < 16) {
            int cc = wn*128 + n*16 + c4;
            float* p = &spart[((size_t)wm*K_C + cc)*3];
            p[0] = m0; p[1] = s1; p[2] = s2;
        }
    }
    __syncthreads();

    if (t < BMR) {
        float4 a0 = topb[(size_t)t*2],        a1 = topb[(size_t)t*2 + 1];
        float4 b0 = topb[(size_t)(BMR+t)*2],  b1 = topb[(size_t)(BMR+t)*2 + 1];
        float v1 = a0.x, v2 = a0.z, v3 = a1.x;
        int   i1 = (int)a0.y, i2 = (int)a0.w, i3 = (int)a1.y;
#define T3INS(DV, DI) do { float d_ = (DV); int id_ = (DI);             \
        bool b3 = d_ < v3, b2 = d_ < v2, b1c = d_ < v1;                 \
        float nv3 = b2 ? v2 : (b3 ? d_ : v3);                           \
        int   ni3 = b2 ? i2 : (b3 ? id_ : i3);                          \
        float nv2 = b1c ? v1 : (b2 ? d_ : v2);                          \
        int   ni2 = b1c ? i1 : (b2 ? id_ : i2);                         \
        v1 = b1c ? d_ : v1; i1 = b1c ? id_ : i1;                        \
        v2 = nv2; i2 = ni2; v3 = nv3; i3 = ni3; } while (0)
        T3INS(b0.x, (int)b0.y);
        T3INS(b0.z, (int)b0.w);
        T3INS(b1.x, (int)b1.y);
#undef T3INS
        int row = R0 + t;
        labels[row] = (float)i1;
        if (v2 - v1 < MARGIN) {
            int slot = atomicAdd(fix_cnt, 1);
            if (slot < MAXFIX) {
                fix_list[slot*4+0] = row;
                fix_list[slot*4+1] = i1;
                fix_list[slot*4+2] = i2;
                fix_list[slot*4+3] = i3;
            }
        }
    }
    {
        int cc = t;
        const float* p0 = &spart[(size_t)cc*3];
        const float* p1 = &spart[((size_t)K_C + cc)*3];
        float M = p0[0], A = p0[1], Bv = p0[2];
        float om = p1[0], oa = p1[1], ob = p1[2];
        float Mn = fminf(M, om);
        float sa = expf(Mn - M), sb = expf(Mn - om);
        A = A*sa + oa*sb; Bv = Bv*sa + ob*sb;
        float* p = &partials[((size_t)blockIdx.x*K_C + cc)*3];
        p[0] = Mn; p[1] = A; p[2] = Bv;
    }
}

// ---------------- f64 exact compare of flagged top-3 ----------------
__global__ __launch_bounds__(256) void krefB(const float* __restrict__ E,
    const float* __restrict__ C, const int* __restrict__ fix_cnt,
    const int* __restrict__ fix_list, float* __restrict__ labels)
{
    int cnt = *fix_cnt; if (cnt > MAXFIX) cnt = MAXFIX;
    int lane = threadIdx.x & 63;
    int wv = (int)((blockIdx.x * blockDim.x + threadIdx.x) >> 6);
    const int NW = (gridDim.x * blockDim.x) >> 6;
    for (int e = wv; e < cnt; e += NW) {
        int row = fix_list[e*4+0];
        int k1  = fix_list[e*4+1], k2 = fix_list[e*4+2], k3 = fix_list[e*4+3];
        double s1 = 0, s2 = 0, s3 = 0;
        for (int d = lane; d < D_DIM; d += 64) {
            double ed = (double)E[(size_t)row*D_DIM + d];
            double ca = (double)C[(size_t)k1*D_DIM + d];
            double cb = (double)C[(size_t)k2*D_DIM + d];
            double cc = (double)C[(size_t)k3*D_DIM + d];
            s1 += ca*(ca - 2.0*ed);     // c^2 - 2ec ; e^2 cancels in compare
            s2 += cb*(cb - 2.0*ed);
            s3 += cc*(cc - 2.0*ed);
        }
#pragma unroll
        for (int msk = 32; msk; msk >>= 1) {
            s1 += __shfl_down(s1, msk, 64);
            s2 += __shfl_down(s2, msk, 64);
            s3 += __shfl_down(s3, msk, 64);
        }
        if (lane == 0) {
            double bv = s1; int bk = k1;
            if (s2 < bv || (s2 == bv && k2 < bk)) { bv = s2; bk = k2; }
            if (s3 < bv || (s3 == bv && k3 < bk)) { bv = s3; bk = k3; }
            labels[row] = (float)bk;
        }
    }
}

// ---------------- per-centroid global combine ----------------
__global__ __launch_bounds__(256) void kcol(const float* __restrict__ partials,
                                            float* __restrict__ colloss, int NB)
{
    __shared__ float Wm[4], Wa[4], Wb[4];
    const int c = blockIdx.x;
    const int t = threadIdx.x;
    float M = FLT_MAX, A = 0.f, Bv = 0.f;
    for (int b = t; b < NB; b += 256) {
        const float* p = &partials[((size_t)b*K_C + c)*3];
        float om = p[0], oa = p[1], ob = p[2];
        float Mn = fminf(M, om);
        float sa = expf(Mn - M), sb = expf(Mn - om);
        A = A*sa + oa*sb; Bv = Bv*sa + ob*sb; M = Mn;
    }
    for (int msk = 1; msk < 64; msk <<= 1) {
        float om = __shfl_xor(M, msk, 64);
        float oa = __shfl_xor(A, msk, 64);
        float ob = __shfl_xor(Bv, msk, 64);
        float Mn = fminf(M, om);
        float sa = expf(Mn - M), sb = expf(Mn - om);
        A = A*sa + oa*sb; Bv = Bv*sa + ob*sb; M = Mn;
    }
    int lane = t & 63, wv = t >> 6;
    if (lane == 0) { Wm[wv] = M; Wa[wv] = A; Wb[wv] = Bv; }
    __syncthreads();
    if (t == 0) {
#pragma unroll
        for (int i = 1; i < 4; ++i) {
            float om = Wm[i], oa = Wa[i], ob = Wb[i];
            float Mn = fminf(M, om);
            float sa = expf(Mn - M), sb = expf(Mn - om);
            A = A*sa + oa*sb; Bv = Bv*sa + ob*sb; M = Mn;
        }
        colloss[c] = Bv / A;
    }
}

// ---------------- final mean over centroids ----------------
__global__ __launch_bounds__(256) void kfinal(const float* __restrict__ colloss,
                                              float* __restrict__ out)
{
    __shared__ float Ws[4];
    int t = threadIdx.x;
    float v = colloss[t];
    for (int msk = 1; msk < 64; msk <<= 1) v += __shfl_xor(v, msk, 64);
    if ((t & 63) == 0) Ws[t >> 6] = v;
    __syncthreads();
    if (t == 0) out[0] = (Ws[0] + Ws[1] + Ws[2] + Ws[3]) / 256.0f;
}

extern "C" void kernel_launch(void* const* d_in, const int* in_sizes, int n_in,
                              void* d_out, int out_size, void* d_ws, size_t ws_size,
                              hipStream_t stream)
{
    const float* E = (const float*)d_in[0];
    const float* C = (const float*)d_in[1];
    float* out = (float*)d_out;

    const int Bn = in_sizes[0] / D_DIM;      // 65536
    const int NB = Bn / BMR;                 // 1024

    char* ws = (char*)d_ws;
    float* c2f      = (float*)ws;                                  // 1 KB
    int*   fix_cnt  = (int*)(ws + 1024);
    int*   fix_list = (int*)(ws + 1088);                           // MAXFIX*16
    short* Cimg     = (short*)(ws + 1088 + MAXFIX*16);             // 384 KB
    float* partials = (float*)((char*)Cimg + (size_t)NCH*16384);   // NB*256*3*4 = 3 MB
    float* colloss  = partials + (size_t)NB*K_C*3;
    float* labels   = out + 1;

    kprep <<<K_C, 256, 0, stream>>>(C, Cimg, c2f, fix_cnt);
    kdist <<<NB,  256, 0, stream>>>(E, Cimg, c2f, labels, partials,
                                    fix_cnt, fix_list);
    krefB <<<128, 256, 0, stream>>>(E, C, fix_cnt, fix_list, labels);
    kcol  <<<K_C, 256, 0, stream>>>(partials, colloss, NB);
    kfinal<<<1,   256, 0, stream>>>(colloss, out);
}